// Round 7
// baseline (218.281 us; speedup 1.0000x reference)
//
#include <hip/hip_runtime.h>

#define IMG 1024
#define OUTW 1018
#define RS 32                  // output rows owned per strip
#define NSTRIP 32              // 32*32 = 1024: strips tile rows exactly
#define NXW 4                  // waves across width: 4*256 = 1024 cols
#define NBATCH 16
#define NWAVE (NBATCH * NSTRIP * NXW)  // 2048 working waves
#define NBLK (NWAVE / 4)               // 512 blocks = exactly 2 blocks/CU, balanced
#define NSTEP (RS + 8)                 // 40 row-steps per strip
#define NTC ((NSTEP + 8) / 9)          // 5 outer ring cycles (45 slots, 5 skipped)
#define EPSF 2.2204460492503131e-16f
#define INV81 (1.0f / 81.0f)

// Pack two f32 -> one reg of 2 bf16 via HW v_cvt_pk_bf16_f32 (RNE, 1 inst).
// ROCm's __float22bfloat162_rn lowers to a software RNE sequence (~4-5 insts
// per value); the HW op is bit-identical RNE so results are unchanged.
__device__ __forceinline__ unsigned pk_bf16(float lo, float hi) {
  unsigned u;
  asm("v_cvt_pk_bf16_f32 %0, %1, %2" : "=v"(u) : "v"(lo), "v"(hi));
  return u;
}
__device__ __forceinline__ float bf_lo(unsigned u) {
  return __uint_as_float(u << 16);
}
__device__ __forceinline__ float bf_hi(unsigned u) {
  return __uint_as_float(u & 0xffff0000u);
}

// Linear horizontal 9-sum window update (bf16 ring for exact cancel).
__device__ __forceinline__ void hsum_update(const float* __restrict__ arr,
                                            float* __restrict__ wX,
                                            unsigned* __restrict__ g) {
  float h0 = arr[0] + arr[1] + arr[2] + arr[3] + arr[4] + arr[5] + arr[6] +
             arr[7] + arr[8];
  float h1 = h0 - arr[0] + arr[9];
  float h2 = h1 - arr[1] + arr[10];
  float h3 = h2 - arr[2] + arr[11];
  unsigned p0 = pk_bf16(h0, h1);
  unsigned p1 = pk_bf16(h2, h3);
  wX[0] += bf_lo(p0) - bf_lo(g[0]);
  wX[1] += bf_hi(p0) - bf_hi(g[0]);
  wX[2] += bf_lo(p1) - bf_lo(g[1]);
  wX[3] += bf_hi(p1) - bf_hi(g[1]);
  g[0] = p0;
  g[1] = p1;
}

// Quadratic (a[p]*b[p]) horizontal 9-sum window update, fmaf-fused.
__device__ __forceinline__ void hsum_update_sq(const float* __restrict__ a,
                                               const float* __restrict__ b,
                                               float* __restrict__ wX,
                                               unsigned* __restrict__ g) {
  float h0 = a[0] * b[0];
  h0 = fmaf(a[1], b[1], h0); h0 = fmaf(a[2], b[2], h0);
  h0 = fmaf(a[3], b[3], h0); h0 = fmaf(a[4], b[4], h0);
  h0 = fmaf(a[5], b[5], h0); h0 = fmaf(a[6], b[6], h0);
  h0 = fmaf(a[7], b[7], h0); h0 = fmaf(a[8], b[8], h0);
  float h1 = fmaf(a[9],  b[9],  fmaf(-a[0], b[0], h0));
  float h2 = fmaf(a[10], b[10], fmaf(-a[1], b[1], h1));
  float h3 = fmaf(a[11], b[11], fmaf(-a[2], b[2], h2));
  unsigned p0 = pk_bf16(h0, h1);
  unsigned p1 = pk_bf16(h2, h3);
  wX[0] += bf_lo(p0) - bf_lo(g[0]);
  wX[1] += bf_hi(p0) - bf_hi(g[0]);
  wX[2] += bf_lo(p1) - bf_lo(g[1]);
  wX[3] += bf_hi(p1) - bf_hi(g[1]);
  g[0] = p0;
  g[1] = p1;
}

// launch_bounds(256,1): (256,4) forces a 64-VGPR target -> 315 MB scratch
// spill (round 1). VGPR MUST stay <=128: round 6 showed 140 VGPR halves
// occupancy (cliff at 128) and costs 1.5x.
__global__ __launch_bounds__(256, 1) void fused_kernel(
    const float* __restrict__ I, const float* __restrict__ J,
    double2* __restrict__ partial) {
  const int lane = threadIdx.x & 63;
  const int wid = blockIdx.x * 4 + (threadIdx.x >> 6);
  float acc_cc = 0.f, acc_sm = 0.f;
  {
    const int b = wid / (NSTRIP * NXW);
    const int rem = wid - b * (NSTRIP * NXW);
    const int strip = rem / NXW;
    const int xw = rem - strip * NXW;
    const int R0 = strip * RS;
    const int base = xw * 256;               // wave's first column
    const int c0 = base + 4 * lane;          // lane's first owned column
    // Edge-patch lanes: lane 0 loads cols base-4..base-1 (left halo .w),
    // lane 62 loads base+256..259, lane 63 loads base+260..263 (right halo).
    // On image borders (xw==0 left, xw==3 right) the patch is NOT loaded:
    // pre-zeroed P registers then implement the conv zero-pad for free.
    int cp = c0;
    if (lane == 0)  cp = base - 4;
    if (lane == 62) cp = base + 256;
    if (lane == 63) cp = base + 260;
    cp = min(max(cp, 0), IMG - 4);           // safe addr even on masked-off lanes
    const bool do_patch = (lane == 0 && xw > 0) || (lane >= 62 && xw < 3);
    const bool isL  = (lane == 0);
    const bool isE1 = (lane == 63);
    const bool isE2 = (lane >= 62);
    const float* Ib = I + (size_t)b * (IMG * IMG);
    const float* Jb = J + (size_t)b * (IMG * IMG);

    // bf16-packed ring: 9 rows x 5 quantities x 4 cols = 90 VGPRs
    unsigned gI[9][2], gJ[9][2], gII[9][2], gJJ[9][2], gIJ[9][2];
#pragma unroll
    for (int k = 0; k < 9; ++k) {
      gI[k][0] = 0u; gI[k][1] = 0u; gJ[k][0] = 0u; gJ[k][1] = 0u;
      gII[k][0] = 0u; gII[k][1] = 0u; gJJ[k][0] = 0u; gJJ[k][1] = 0u;
      gIJ[k][0] = 0u; gIJ[k][1] = 0u;
    }
    float wI[4] = {0,0,0,0}, wJ[4] = {0,0,0,0}, wII[4] = {0,0,0,0},
          wJJ[4] = {0,0,0,0}, wIJ[4] = {0,0,0,0};
    float prevI[4] = {0,0,0,0};
    float4 PI = make_float4(0.f, 0.f, 0.f, 0.f);
    float4 PJ = make_float4(0.f, 0.f, 0.f, 0.f);

    for (int tc = 0; tc < NTC; ++tc) {
#pragma unroll
      for (int u = 0; u < 9; ++u) {
        const int t = tc * 9 + u;
        if (t < NSTEP) {
          const int r = R0 - 1 + t;      // input row
          float iw[12], jw[12];
          if (r >= 0 && r < IMG) {       // wave-uniform
            const float* rpI = Ib + ((size_t)r << 10);
            const float* rpJ = Jb + ((size_t)r << 10);
            // Loads per image: 1 full-wave float4 + 1 masked float4 (3 lanes).
            float4 A1 = *(const float4*)(rpI + c0);
            float4 B1 = *(const float4*)(rpJ + c0);
            if (do_patch) {              // divergent, 3 lanes
              PI = *(const float4*)(rpI + cp);
              PJ = *(const float4*)(rpJ + cp);
            }
            // left halo (col c0-1) from lane-1's A1.w; lane 0 from patch
            float lhI = __shfl_up(A1.w, 1), lhJ = __shfl_up(B1.w, 1);
            // lane 63's right halo cols base+256..259 from lane 62's patch
            float s5I = __shfl_up(PI.x, 1), s6I = __shfl_up(PI.y, 1);
            float s7I = __shfl_up(PI.z, 1), s8I = __shfl_up(PI.w, 1);
            float s5J = __shfl_up(PJ.x, 1), s6J = __shfl_up(PJ.y, 1);
            float s7J = __shfl_up(PJ.z, 1), s8J = __shfl_up(PJ.w, 1);
            // right halo from neighbor lanes
            float d5I = __shfl_down(A1.x, 1), d6I = __shfl_down(A1.y, 1);
            float d7I = __shfl_down(A1.z, 1), d8I = __shfl_down(A1.w, 1);
            float d9I = __shfl_down(A1.x, 2), d10I = __shfl_down(A1.y, 2);
            float d11I = __shfl_down(A1.z, 2);
            float d5J = __shfl_down(B1.x, 1), d6J = __shfl_down(B1.y, 1);
            float d7J = __shfl_down(B1.z, 1), d8J = __shfl_down(B1.w, 1);
            float d9J = __shfl_down(B1.x, 2), d10J = __shfl_down(B1.y, 2);
            float d11J = __shfl_down(B1.z, 2);
            iw[0] = isL ? PI.w : lhI;         jw[0] = isL ? PJ.w : lhJ;
            iw[1] = A1.x; iw[2] = A1.y; iw[3] = A1.z; iw[4] = A1.w;
            jw[1] = B1.x; jw[2] = B1.y; jw[3] = B1.z; jw[4] = B1.w;
            iw[5] = isE1 ? s5I : d5I;  jw[5] = isE1 ? s5J : d5J;
            iw[6] = isE1 ? s6I : d6I;  jw[6] = isE1 ? s6J : d6J;
            iw[7] = isE1 ? s7I : d7I;  jw[7] = isE1 ? s7J : d7J;
            iw[8] = isE1 ? s8I : d8I;  jw[8] = isE1 ? s8J : d8J;
            iw[9]  = isE2 ? PI.x : d9I;   jw[9]  = isE2 ? PJ.x : d9J;
            iw[10] = isE2 ? PI.y : d10I;  jw[10] = isE2 ? PJ.y : d10J;
            iw[11] = isE2 ? PI.z : d11I;  jw[11] = isE2 ? PJ.z : d11J;
          } else {
#pragma unroll
            for (int p = 0; p < 12; ++p) { iw[p] = 0.f; jw[p] = 0.f; }
          }

          hsum_update(iw, wI, gI[u]);
          hsum_update(jw, wJ, gJ[u]);
          hsum_update_sq(iw, iw, wII, gII[u]);
          hsum_update_sq(jw, jw, wJJ, gJJ[u]);
          hsum_update_sq(iw, jw, wIJ, gIJ[u]);

          // smoothness dy: pairs (r-1, r) with r-1 owned by this strip
          if (r >= R0 + 1 && r <= R0 + RS && r <= IMG - 1) {   // uniform
#pragma unroll
            for (int q = 0; q < 4; ++q) {
              float d = iw[1 + q] - prevI[q];
              acc_sm = fmaf(d, d, acc_sm);
            }
          }
          // smoothness dx at owned rows
          if (r >= R0 && r <= R0 + RS - 1 && r <= IMG - 1) {   // uniform
#pragma unroll
            for (int q = 0; q < 4; ++q) {
              float d = iw[2 + q] - iw[1 + q];
              d = (c0 + q < IMG - 1) ? d : 0.f;
              acc_sm = fmaf(d, d, acc_sm);
            }
          }
          prevI[0] = iw[1]; prevI[1] = iw[2]; prevI[2] = iw[3]; prevI[3] = iw[4];

          // emit output row oy = R0 + t - 8 once window complete
          if (t >= 8) {                                        // uniform
            const int oy = R0 + t - 8;
            if (oy < OUTW) {                                   // uniform
#pragma unroll
              for (int q = 0; q < 4; ++q) {
                if (c0 + q < OUTW) {
                  float cross = fmaf(-(wI[q] * wJ[q]), INV81, wIJ[q]);
                  float iva   = fmaf(-(wI[q] * wI[q]), INV81, wII[q]);
                  float jva   = fmaf(-(wJ[q] * wJ[q]), INV81, wJJ[q]);
                  float den   = fmaf(iva, jva, EPSF);
                  acc_cc += cross * cross * __builtin_amdgcn_rcpf(den);
                }
              }
            }
          }
        }
      }
    }
  }

  // per-wave shuffle reduce, then per-block LDS reduce; one double2 per block
  float vc = acc_cc, vs = acc_sm;
#pragma unroll
  for (int off = 32; off > 0; off >>= 1) {
    vc += __shfl_down(vc, off);
    vs += __shfl_down(vs, off);
  }
  __shared__ double2 red[4];
  if (lane == 0) red[threadIdx.x >> 6] = make_double2((double)vc, (double)vs);
  __syncthreads();
  if (threadIdx.x == 0) {
    partial[blockIdx.x] = make_double2(red[0].x + red[1].x + red[2].x + red[3].x,
                                       red[0].y + red[1].y + red[2].y + red[3].y);
  }
}

__global__ __launch_bounds__(256) void fin_kernel(const double2* __restrict__ partial,
                                                  float* __restrict__ out) {
  double s_cc = 0.0, s_sm = 0.0;
  for (int i = threadIdx.x; i < NBLK; i += 256) {
    double2 p = partial[i];
    s_cc += p.x; s_sm += p.y;
  }
#pragma unroll
  for (int off = 32; off > 0; off >>= 1) {
    s_cc += __shfl_down(s_cc, off);
    s_sm += __shfl_down(s_sm, off);
  }
  __shared__ double r1[4], r2[4];
  if ((threadIdx.x & 63) == 0) { r1[threadIdx.x >> 6] = s_cc; r2[threadIdx.x >> 6] = s_sm; }
  __syncthreads();
  if (threadIdx.x == 0) {
    const double cc = (r1[0] + r1[1] + r1[2] + r1[3]) /
                      (double)((size_t)NBATCH * OUTW * OUTW);
    const double sm = (r2[0] + r2[1] + r2[2] + r2[3]) /
                      (2.0 * (double)((size_t)NBATCH * IMG * (IMG - 1)));
    out[0] = (float)(-cc + 0.1 * sm);
  }
}

extern "C" void kernel_launch(void* const* d_in, const int* in_sizes, int n_in,
                              void* d_out, int out_size, void* d_ws, size_t ws_size,
                              hipStream_t stream) {
  const float* y  = (const float*)d_in[0];
  const float* yt = (const float*)d_in[1];
  float* out = (float*)d_out;
  double2* partial = (double2*)d_ws;
  fused_kernel<<<NBLK, 256, 0, stream>>>(y, yt, partial);
  fin_kernel<<<1, 256, 0, stream>>>(partial, out);
}

// Round 8
// 194.212 us; speedup vs baseline: 1.1239x; 1.1239x over previous
//
#include <hip/hip_runtime.h>
#include <hip/hip_bf16.h>

#define IMG 1024
#define OUTW 1018
#define RS 32                  // output rows owned per strip
#define NSTRIP 32              // 32*32 = 1024: strips tile rows exactly
#define NXW 4                  // waves across width: 4*256 = 1024 cols
#define NBATCH 16
#define NWAVE (NBATCH * NSTRIP * NXW)  // 2048 working waves
#define NBLK (NWAVE / 4)               // 512 blocks = exactly 2 blocks/CU, balanced
#define NSTEP (RS + 8)                 // 40 row-steps per strip
#define NTC ((NSTEP + 8) / 9)          // 5 outer ring cycles (45 slots, 5 skipped)
#define EPSF 2.2204460492503131e-16f
#define INV81 (1.0f / 81.0f)

// Linear horizontal 9-sum window update (bf16 ring for exact cancel).
__device__ __forceinline__ void hsum_update(const float* __restrict__ arr,
                                            float* __restrict__ wX,
                                            __hip_bfloat162* __restrict__ g) {
  float h0 = arr[0] + arr[1] + arr[2] + arr[3] + arr[4] + arr[5] + arr[6] +
             arr[7] + arr[8];
  float h1 = h0 - arr[0] + arr[9];
  float h2 = h1 - arr[1] + arr[10];
  float h3 = h2 - arr[2] + arr[11];
  __hip_bfloat162 plo = __float22bfloat162_rn(make_float2(h0, h1));
  __hip_bfloat162 phi = __float22bfloat162_rn(make_float2(h2, h3));
  float2 nlo = __bfloat1622float2(plo), nhi = __bfloat1622float2(phi);
  float2 olo = __bfloat1622float2(g[0]), ohi = __bfloat1622float2(g[1]);
  wX[0] += nlo.x - olo.x;
  wX[1] += nlo.y - olo.y;
  wX[2] += nhi.x - ohi.x;
  wX[3] += nhi.y - ohi.y;
  g[0] = plo;
  g[1] = phi;
}

// Quadratic (a[p]*b[p]) horizontal 9-sum window update, fmaf-fused.
__device__ __forceinline__ void hsum_update_sq(const float* __restrict__ a,
                                               const float* __restrict__ b,
                                               float* __restrict__ wX,
                                               __hip_bfloat162* __restrict__ g) {
  float h0 = a[0] * b[0];
  h0 = fmaf(a[1], b[1], h0); h0 = fmaf(a[2], b[2], h0);
  h0 = fmaf(a[3], b[3], h0); h0 = fmaf(a[4], b[4], h0);
  h0 = fmaf(a[5], b[5], h0); h0 = fmaf(a[6], b[6], h0);
  h0 = fmaf(a[7], b[7], h0); h0 = fmaf(a[8], b[8], h0);
  float h1 = fmaf(a[9],  b[9],  fmaf(-a[0], b[0], h0));
  float h2 = fmaf(a[10], b[10], fmaf(-a[1], b[1], h1));
  float h3 = fmaf(a[11], b[11], fmaf(-a[2], b[2], h2));
  __hip_bfloat162 plo = __float22bfloat162_rn(make_float2(h0, h1));
  __hip_bfloat162 phi = __float22bfloat162_rn(make_float2(h2, h3));
  float2 nlo = __bfloat1622float2(plo), nhi = __bfloat1622float2(phi);
  float2 olo = __bfloat1622float2(g[0]), ohi = __bfloat1622float2(g[1]);
  wX[0] += nlo.x - olo.x;
  wX[1] += nlo.y - olo.y;
  wX[2] += nhi.x - ohi.x;
  wX[3] += nhi.y - ohi.y;
  g[0] = plo;
  g[1] = phi;
}

// launch_bounds(256,1): (256,4) forces a 64-VGPR target -> 315 MB scratch
// spill (round 1). VGPR MUST stay <=128: rounds 6/7 showed 132-140 VGPR
// halves occupancy (cliff at 128) and costs 1.5-2x.
__global__ __launch_bounds__(256, 1) void fused_kernel(
    const float* __restrict__ I, const float* __restrict__ J,
    double2* __restrict__ partial) {
  const int lane = threadIdx.x & 63;
  const int wid = blockIdx.x * 4 + (threadIdx.x >> 6);
  float acc_cc = 0.f, acc_sm = 0.f;
  {
    const int b = wid / (NSTRIP * NXW);
    const int rem = wid - b * (NSTRIP * NXW);
    const int strip = rem / NXW;
    const int xw = rem - strip * NXW;
    const int R0 = strip * RS;
    const int base = xw * 256;               // wave's first column
    const int c0 = base + 4 * lane;          // lane's first owned column
    // Edge-patch lanes: lane 0 loads cols base-4..base-1 (left halo .w),
    // lane 62 loads base+256..259, lane 63 loads base+260..263 (right halo).
    // On image borders (xw==0 left, xw==3 right) the patch is NOT loaded:
    // pre-zeroed P registers then implement the conv zero-pad for free.
    int cp = c0;
    if (lane == 0)  cp = base - 4;
    if (lane == 62) cp = base + 256;
    if (lane == 63) cp = base + 260;
    cp = min(max(cp, 0), IMG - 4);           // safe addr even on masked-off lanes
    const bool do_patch = (lane == 0 && xw > 0) || (lane >= 62 && xw < 3);
    const bool isL  = (lane == 0);
    const bool isE1 = (lane == 63);
    const bool isE2 = (lane >= 62);
    const float* Ib = I + (size_t)b * (IMG * IMG);
    const float* Jb = J + (size_t)b * (IMG * IMG);

    // bf16-packed ring: 9 rows x 5 quantities x 4 cols = 90 VGPRs
    __hip_bfloat162 gI[9][2], gJ[9][2], gII[9][2], gJJ[9][2], gIJ[9][2];
    const __hip_bfloat162 z2 = __float22bfloat162_rn(make_float2(0.f, 0.f));
#pragma unroll
    for (int k = 0; k < 9; ++k) {
      gI[k][0] = z2; gI[k][1] = z2; gJ[k][0] = z2; gJ[k][1] = z2;
      gII[k][0] = z2; gII[k][1] = z2; gJJ[k][0] = z2; gJJ[k][1] = z2;
      gIJ[k][0] = z2; gIJ[k][1] = z2;
    }
    float wI[4] = {0,0,0,0}, wJ[4] = {0,0,0,0}, wII[4] = {0,0,0,0},
          wJJ[4] = {0,0,0,0}, wIJ[4] = {0,0,0,0};
    float prevI[4] = {0,0,0,0};
    float4 PI = make_float4(0.f, 0.f, 0.f, 0.f);
    float4 PJ = make_float4(0.f, 0.f, 0.f, 0.f);
    // A1/B1 hold row r for the CURRENT step, loaded at the tail of the
    // PREVIOUS step (register-overlay prefetch: A1 is dead between the
    // gather phase and the tail, so this adds ZERO peak liveness --
    // unlike round 6's separate A1n/B1n rotate which crossed the cliff).
    float4 A1 = make_float4(0.f, 0.f, 0.f, 0.f);
    float4 B1 = make_float4(0.f, 0.f, 0.f, 0.f);
    {
      const int r0 = R0 - 1;
      if (r0 >= 0) {                         // uniform (false only for strip 0)
        const float* rpI = Ib + ((size_t)r0 << 10);
        const float* rpJ = Jb + ((size_t)r0 << 10);
        A1 = *(const float4*)(rpI + c0);
        B1 = *(const float4*)(rpJ + c0);
        if (do_patch) {
          PI = *(const float4*)(rpI + cp);
          PJ = *(const float4*)(rpJ + cp);
        }
      }
    }

    for (int tc = 0; tc < NTC; ++tc) {
#pragma unroll
      for (int u = 0; u < 9; ++u) {
        const int t = tc * 9 + u;
        if (t < NSTEP) {
          const int r = R0 - 1 + t;      // input row (data already in A1/B1)
          float iw[12], jw[12];
          if (r >= 0 && r < IMG) {       // wave-uniform
            // left halo (col c0-1) from lane-1's A1.w; lane 0 from patch
            float lhI = __shfl_up(A1.w, 1), lhJ = __shfl_up(B1.w, 1);
            // lane 63's right halo cols base+256..259 from lane 62's patch
            float s5I = __shfl_up(PI.x, 1), s6I = __shfl_up(PI.y, 1);
            float s7I = __shfl_up(PI.z, 1), s8I = __shfl_up(PI.w, 1);
            float s5J = __shfl_up(PJ.x, 1), s6J = __shfl_up(PJ.y, 1);
            float s7J = __shfl_up(PJ.z, 1), s8J = __shfl_up(PJ.w, 1);
            // right halo from neighbor lanes
            float d5I = __shfl_down(A1.x, 1), d6I = __shfl_down(A1.y, 1);
            float d7I = __shfl_down(A1.z, 1), d8I = __shfl_down(A1.w, 1);
            float d9I = __shfl_down(A1.x, 2), d10I = __shfl_down(A1.y, 2);
            float d11I = __shfl_down(A1.z, 2);
            float d5J = __shfl_down(B1.x, 1), d6J = __shfl_down(B1.y, 1);
            float d7J = __shfl_down(B1.z, 1), d8J = __shfl_down(B1.w, 1);
            float d9J = __shfl_down(B1.x, 2), d10J = __shfl_down(B1.y, 2);
            float d11J = __shfl_down(B1.z, 2);
            iw[0] = isL ? PI.w : lhI;         jw[0] = isL ? PJ.w : lhJ;
            iw[1] = A1.x; iw[2] = A1.y; iw[3] = A1.z; iw[4] = A1.w;
            jw[1] = B1.x; jw[2] = B1.y; jw[3] = B1.z; jw[4] = B1.w;
            iw[5] = isE1 ? s5I : d5I;  jw[5] = isE1 ? s5J : d5J;
            iw[6] = isE1 ? s6I : d6I;  jw[6] = isE1 ? s6J : d6J;
            iw[7] = isE1 ? s7I : d7I;  jw[7] = isE1 ? s7J : d7J;
            iw[8] = isE1 ? s8I : d8I;  jw[8] = isE1 ? s8J : d8J;
            iw[9]  = isE2 ? PI.x : d9I;   jw[9]  = isE2 ? PJ.x : d9J;
            iw[10] = isE2 ? PI.y : d10I;  jw[10] = isE2 ? PJ.y : d10J;
            iw[11] = isE2 ? PI.z : d11I;  jw[11] = isE2 ? PJ.z : d11J;
          } else {
#pragma unroll
            for (int p = 0; p < 12; ++p) { iw[p] = 0.f; jw[p] = 0.f; }
          }

          hsum_update(iw, wI, gI[u]);
          hsum_update(jw, wJ, gJ[u]);
          hsum_update_sq(iw, iw, wII, gII[u]);
          hsum_update_sq(jw, jw, wJJ, gJJ[u]);
          hsum_update_sq(iw, jw, wIJ, gIJ[u]);

          // smoothness dy: pairs (r-1, r) with r-1 owned by this strip
          if (r >= R0 + 1 && r <= R0 + RS && r <= IMG - 1) {   // uniform
#pragma unroll
            for (int q = 0; q < 4; ++q) {
              float d = iw[1 + q] - prevI[q];
              acc_sm = fmaf(d, d, acc_sm);
            }
          }
          // smoothness dx at owned rows
          if (r >= R0 && r <= R0 + RS - 1 && r <= IMG - 1) {   // uniform
#pragma unroll
            for (int q = 0; q < 4; ++q) {
              float d = iw[2 + q] - iw[1 + q];
              d = (c0 + q < IMG - 1) ? d : 0.f;
              acc_sm = fmaf(d, d, acc_sm);
            }
          }
          prevI[0] = iw[1]; prevI[1] = iw[2]; prevI[2] = iw[3]; prevI[3] = iw[4];

          // ---- tail prefetch: load row r+1 into A1/B1/PI/PJ (dead since
          // gather). emit + loop-back + next gather's issue cover the
          // latency. Guards are wave-uniform; skipped loads leave zeros
          // (border pad) or stale data that the next step's zero-branch
          // never reads.
          {
            const int rn = r + 1;
            if (t + 1 < NSTEP && rn < IMG) {                   // uniform
              const float* rpI = Ib + ((size_t)rn << 10);
              const float* rpJ = Jb + ((size_t)rn << 10);
              A1 = *(const float4*)(rpI + c0);
              B1 = *(const float4*)(rpJ + c0);
              if (do_patch) {          // divergent, 3 lanes
                PI = *(const float4*)(rpI + cp);
                PJ = *(const float4*)(rpJ + cp);
              }
            }
          }

          // emit output row oy = R0 + t - 8 once window complete
          if (t >= 8) {                                        // uniform
            const int oy = R0 + t - 8;
            if (oy < OUTW) {                                   // uniform
#pragma unroll
              for (int q = 0; q < 4; ++q) {
                if (c0 + q < OUTW) {
                  float cross = fmaf(-(wI[q] * wJ[q]), INV81, wIJ[q]);
                  float iva   = fmaf(-(wI[q] * wI[q]), INV81, wII[q]);
                  float jva   = fmaf(-(wJ[q] * wJ[q]), INV81, wJJ[q]);
                  float den   = fmaf(iva, jva, EPSF);
                  acc_cc += cross * cross * __builtin_amdgcn_rcpf(den);
                }
              }
            }
          }
        }
      }
    }
  }

  // per-wave shuffle reduce, then per-block LDS reduce; one double2 per block
  float vc = acc_cc, vs = acc_sm;
#pragma unroll
  for (int off = 32; off > 0; off >>= 1) {
    vc += __shfl_down(vc, off);
    vs += __shfl_down(vs, off);
  }
  __shared__ double2 red[4];
  if (lane == 0) red[threadIdx.x >> 6] = make_double2((double)vc, (double)vs);
  __syncthreads();
  if (threadIdx.x == 0) {
    partial[blockIdx.x] = make_double2(red[0].x + red[1].x + red[2].x + red[3].x,
                                       red[0].y + red[1].y + red[2].y + red[3].y);
  }
}

__global__ __launch_bounds__(256) void fin_kernel(const double2* __restrict__ partial,
                                                  float* __restrict__ out) {
  double s_cc = 0.0, s_sm = 0.0;
  for (int i = threadIdx.x; i < NBLK; i += 256) {
    double2 p = partial[i];
    s_cc += p.x; s_sm += p.y;
  }
#pragma unroll
  for (int off = 32; off > 0; off >>= 1) {
    s_cc += __shfl_down(s_cc, off);
    s_sm += __shfl_down(s_sm, off);
  }
  __shared__ double r1[4], r2[4];
  if ((threadIdx.x & 63) == 0) { r1[threadIdx.x >> 6] = s_cc; r2[threadIdx.x >> 6] = s_sm; }
  __syncthreads();
  if (threadIdx.x == 0) {
    const double cc = (r1[0] + r1[1] + r1[2] + r1[3]) /
                      (double)((size_t)NBATCH * OUTW * OUTW);
    const double sm = (r2[0] + r2[1] + r2[2] + r2[3]) /
                      (2.0 * (double)((size_t)NBATCH * IMG * (IMG - 1)));
    out[0] = (float)(-cc + 0.1 * sm);
  }
}

extern "C" void kernel_launch(void* const* d_in, const int* in_sizes, int n_in,
                              void* d_out, int out_size, void* d_ws, size_t ws_size,
                              hipStream_t stream) {
  const float* y  = (const float*)d_in[0];
  const float* yt = (const float*)d_in[1];
  float* out = (float*)d_out;
  double2* partial = (double2*)d_ws;
  fused_kernel<<<NBLK, 256, 0, stream>>>(y, yt, partial);
  fin_kernel<<<1, 256, 0, stream>>>(partial, out);
}